// Round 1
// baseline (858.345 us; speedup 1.0000x reference)
//
#include <hip/hip_runtime.h>
#include <cstdint>

#define T_STEPS 512
#define BT 16            // batch rows per block
#define BLOCK 512        // 8 waves
#define RS_H 136         // hcat row stride (bf16 elems): 128 data + 8 pad
#define RS_G 260         // gate buffer row stride (fp32): 256 + 4 pad (breaks quad bank aliasing)

typedef __attribute__((ext_vector_type(8))) short bf16x8;
typedef __attribute__((ext_vector_type(4))) float f32x4;

__device__ __forceinline__ unsigned short f2bf(float f) {
    union { float f; unsigned u; } v; v.f = f;
    unsigned r = v.u + 0x7fffu + ((v.u >> 16) & 1u);   // RNE
    return (unsigned short)(r >> 16);
}
__device__ __forceinline__ float sigm(float x) {
    return __builtin_amdgcn_rcpf(1.0f + __expf(-x));
}
__device__ __forceinline__ float tanh_fast(float x) {
    return 1.0f - 2.0f * __builtin_amdgcn_rcpf(__expf(2.0f * x) + 1.0f);
}
// Build a bf16 B-fragment (8 consecutive k of one weight row) from global fp32
__device__ __forceinline__ bf16x8 load_wfrag(const float* __restrict__ wrow, int off) {
    f32x4 lo = *(const f32x4*)(wrow + off);
    f32x4 hi = *(const f32x4*)(wrow + off + 4);
    union { bf16x8 v; unsigned short s[8]; } u;
    u.s[0] = f2bf(lo[0]); u.s[1] = f2bf(lo[1]); u.s[2] = f2bf(lo[2]); u.s[3] = f2bf(lo[3]);
    u.s[4] = f2bf(hi[0]); u.s[5] = f2bf(hi[1]); u.s[6] = f2bf(hi[2]); u.s[7] = f2bf(hi[3]);
    return u.v;
}

extern "C" __global__ void __launch_bounds__(BLOCK, 2)
lstm_fused_kernel(const float* __restrict__ x,
                  const float* __restrict__ Wih0, const float* __restrict__ Whh0,
                  const float* __restrict__ bih0, const float* __restrict__ bhh0,
                  const float* __restrict__ Wih1, const float* __restrict__ Whh1,
                  const float* __restrict__ bih1, const float* __restrict__ bhh1,
                  const float* __restrict__ Wfc,  const float* __restrict__ bfc,
                  float* __restrict__ out)
{
    __shared__ unsigned short hc[BT * RS_H];  // [m][0:64)=h0 bf16, [64:128)=h1 bf16
    __shared__ float gb[BT * RS_G];           // gate pre-activations fp32 (and final h1 fp32)

    const int tid  = threadIdx.x;
    const int b0   = blockIdx.x * BT;
    const int lane = tid & 63;
    const int wv   = tid >> 6;        // wave 0..7
    const int n16  = lane & 15;       // frag row/col within 16
    const int quad = lane >> 4;       // 0..3
    const int g0   = wv * 32;         // this wave's gate-tile base (two 16-wide tiles)

    // zero h state
    for (int i = tid; i < BT * RS_H; i += BLOCK) hc[i] = 0;

    // ---- loop-invariant weight fragments (B-operand, gemm_bt layout: lane holds
    //      W[g0+n16][ko+quad*8 .. +8)) hoisted into registers, bf16 ----
    bf16x8 w0A[2], w0B[2], wiA[2], wiB[2], whA[2], whB[2];
#pragma unroll
    for (int kk = 0; kk < 2; ++kk) {
        int off = kk * 32 + quad * 8;
        w0A[kk] = load_wfrag(Whh0 + (g0 + n16) * 64, off);
        w0B[kk] = load_wfrag(Whh0 + (g0 + 16 + n16) * 64, off);
        wiA[kk] = load_wfrag(Wih1 + (g0 + n16) * 64, off);
        wiB[kk] = load_wfrag(Wih1 + (g0 + 16 + n16) * 64, off);
        whA[kk] = load_wfrag(Whh1 + (g0 + n16) * 64, off);
        whB[kk] = load_wfrag(Whh1 + (g0 + 16 + n16) * 64, off);
    }
    // biases folded into MFMA C-init (same value across the 4 row-regs)
    const float b0a = bih0[g0 + n16] + bhh0[g0 + n16];
    const float b0b = bih0[g0 + 16 + n16] + bhh0[g0 + 16 + n16];
    const float b1a = bih1[g0 + n16] + bhh1[g0 + n16];
    const float b1b = bih1[g0 + 16 + n16] + bhh1[g0 + 16 + n16];

    // elementwise mapping: thread owns (m0, l) and (m0+8, l)
    const int l  = tid & 63;
    const int m0 = tid >> 6;
    float wx[4][4];                       // Wih0 rows {q*64+l}, fp32 (x-part stays exact)
#pragma unroll
    for (int q = 0; q < 4; ++q)
#pragma unroll
        for (int c = 0; c < 4; ++c)
            wx[q][c] = Wih0[(q * 64 + l) * 4 + c];

    float c0[2] = {0.f, 0.f}, c1[2] = {0.f, 0.f};
    const f32x4* xv = (const f32x4*)x;

    __syncthreads();

    for (int t = 0; t < T_STEPS; ++t) {
        // ---- Phase A: layer0 recurrent GEMM  G0 = H0 @ Whh0^T + (bih0+bhh0)
        {
            f32x4 accA = {b0a, b0a, b0a, b0a};
            f32x4 accB = {b0b, b0b, b0b, b0b};
#pragma unroll
            for (int kk = 0; kk < 2; ++kk) {
                bf16x8 a = *(const bf16x8*)(hc + n16 * RS_H + kk * 32 + quad * 8);
                accA = __builtin_amdgcn_mfma_f32_16x16x32_bf16(a, w0A[kk], accA, 0, 0, 0);
                accB = __builtin_amdgcn_mfma_f32_16x16x32_bf16(a, w0B[kk], accB, 0, 0, 0);
            }
#pragma unroll
            for (int r = 0; r < 4; ++r) {
                gb[(quad * 4 + r) * RS_G + g0 + n16]      = accA[r];
                gb[(quad * 4 + r) * RS_G + g0 + 16 + n16] = accB[r];
            }
        }
        __syncthreads();

        // ---- Phase B: layer0 elementwise (adds Wih0@x_t in fp32), h0 -> LDS bf16
#pragma unroll
        for (int e = 0; e < 2; ++e) {
            int m = m0 + e * 8;
            f32x4 xt = xv[(size_t)(b0 + m) * T_STEPS + t];
            float gi = gb[m * RS_G + l]       + wx[0][0]*xt[0] + wx[0][1]*xt[1] + wx[0][2]*xt[2] + wx[0][3]*xt[3];
            float gf = gb[m * RS_G + 64 + l]  + wx[1][0]*xt[0] + wx[1][1]*xt[1] + wx[1][2]*xt[2] + wx[1][3]*xt[3];
            float gg = gb[m * RS_G + 128 + l] + wx[2][0]*xt[0] + wx[2][1]*xt[1] + wx[2][2]*xt[2] + wx[2][3]*xt[3];
            float go = gb[m * RS_G + 192 + l] + wx[3][0]*xt[0] + wx[3][1]*xt[1] + wx[3][2]*xt[2] + wx[3][3]*xt[3];
            float iv = sigm(gi), fv = sigm(gf), gv = tanh_fast(gg), ov = sigm(go);
            float cc = fv * c0[e] + iv * gv;
            c0[e] = cc;
            hc[m * RS_H + l] = f2bf(ov * tanh_fast(cc));
        }
        __syncthreads();

        // ---- Phase C: layer1 GEMM  G1 = H0new @ Wih1^T + H1 @ Whh1^T + (bih1+bhh1)
        {
            f32x4 accA = {b1a, b1a, b1a, b1a};
            f32x4 accB = {b1b, b1b, b1b, b1b};
#pragma unroll
            for (int kk = 0; kk < 2; ++kk) {
                bf16x8 a0 = *(const bf16x8*)(hc + n16 * RS_H + kk * 32 + quad * 8);        // h0new
                accA = __builtin_amdgcn_mfma_f32_16x16x32_bf16(a0, wiA[kk], accA, 0, 0, 0);
                accB = __builtin_amdgcn_mfma_f32_16x16x32_bf16(a0, wiB[kk], accB, 0, 0, 0);
                bf16x8 a1 = *(const bf16x8*)(hc + n16 * RS_H + 64 + kk * 32 + quad * 8);   // h1
                accA = __builtin_amdgcn_mfma_f32_16x16x32_bf16(a1, whA[kk], accA, 0, 0, 0);
                accB = __builtin_amdgcn_mfma_f32_16x16x32_bf16(a1, whB[kk], accB, 0, 0, 0);
            }
#pragma unroll
            for (int r = 0; r < 4; ++r) {
                gb[(quad * 4 + r) * RS_G + g0 + n16]      = accA[r];
                gb[(quad * 4 + r) * RS_G + g0 + 16 + n16] = accB[r];
            }
        }
        __syncthreads();

        // ---- Phase D: layer1 elementwise, h1 -> LDS bf16 (+ fp32 copy on last step)
#pragma unroll
        for (int e = 0; e < 2; ++e) {
            int m = m0 + e * 8;
            float gi = gb[m * RS_G + l];
            float gf = gb[m * RS_G + 64 + l];
            float gg = gb[m * RS_G + 128 + l];
            float go = gb[m * RS_G + 192 + l];
            float iv = sigm(gi), fv = sigm(gf), gv = tanh_fast(gg), ov = sigm(go);
            float cc = fv * c1[e] + iv * gv;
            c1[e] = cc;
            float hh = ov * tanh_fast(cc);
            hc[m * RS_H + 64 + l] = f2bf(hh);
            if (t == T_STEPS - 1) gb[m * RS_G + l] = hh;   // own slot only: safe
        }
        __syncthreads();
    }

    // ---- FC head: out[b0+m][k] = h1[m,:] . Wfc[k,:] + bfc[k]   (fp32)
    if (tid < BT * 20) {
        int m = tid / 20, k = tid % 20;
        float acc = bfc[k];
#pragma unroll 8
        for (int j = 0; j < 64; ++j)
            acc += gb[m * RS_G + j] * Wfc[k * 64 + j];
        out[(b0 + m) * 20 + k] = acc;
    }
}

extern "C" void kernel_launch(void* const* d_in, const int* in_sizes, int n_in,
                              void* d_out, int out_size, void* d_ws, size_t ws_size,
                              hipStream_t stream)
{
    (void)in_sizes; (void)n_in; (void)d_ws; (void)ws_size; (void)out_size;
    const float* xp    = (const float*)d_in[0];
    const float* Wih0p = (const float*)d_in[1];
    const float* Whh0p = (const float*)d_in[2];
    const float* bih0p = (const float*)d_in[3];
    const float* bhh0p = (const float*)d_in[4];
    const float* Wih1p = (const float*)d_in[5];
    const float* Whh1p = (const float*)d_in[6];
    const float* bih1p = (const float*)d_in[7];
    const float* bhh1p = (const float*)d_in[8];
    const float* Wfcp  = (const float*)d_in[9];
    const float* bfcp  = (const float*)d_in[10];

    lstm_fused_kernel<<<dim3(256), dim3(BLOCK), 0, stream>>>(
        xp, Wih0p, Whh0p, bih0p, bhh0p, Wih1p, Whh1p, bih1p, bhh1p,
        Wfcp, bfcp, (float*)d_out);
}

// Round 2
// 568.713 us; speedup vs baseline: 1.5093x; 1.5093x over previous
//
#include <hip/hip_runtime.h>
#include <cstdint>

#define BLOCK 512
#define BT 16            // batch rows per block (grid = 4096/16 = 256 = 1 block/CU)
#define RS_H 136         // h row stride in bf16 elems: 128 data (h0|h1) + 8 pad
#define RS_F 68          // hfin row stride (fp32)

typedef __attribute__((ext_vector_type(8))) short bf16x8;
typedef __attribute__((ext_vector_type(4))) float f32x4;

static __device__ __forceinline__ unsigned short f2bf(float f) {
    union { float f; unsigned u; } v; v.f = f;
    unsigned r = v.u + 0x7fffu + ((v.u >> 16) & 1u);   // RNE
    return (unsigned short)(r >> 16);
}
static __device__ __forceinline__ float sigm(float x) {
    return __builtin_amdgcn_rcpf(1.0f + __expf(-x));
}
static __device__ __forceinline__ float tanh_fast(float x) {
    return 1.0f - 2.0f * __builtin_amdgcn_rcpf(__expf(2.0f * x) + 1.0f);
}
static __device__ __forceinline__ bf16x8 load_wfrag(const float* __restrict__ w, int off) {
    union { bf16x8 v; unsigned short s[8]; } u;
#pragma unroll
    for (int j = 0; j < 8; ++j) u.s[j] = f2bf(w[off + j]);
    return u.v;
}

// One block = 16 batch rows. 8 waves: wv>>2 = layer (0/1), wv&3 = 16-col tile.
// Pipeline skew: at iteration `it`, L0-waves compute step it (using h0(it-1)),
// L1-waves compute step it-1 (using h0(it-1), h1(it-2)). Ping-pong h buffers
// => ONE barrier per iteration; gate eltwise runs directly on MFMA accumulators
// (C/D layout: col = lane&15, row = quad*4 + reg) with zero gate-LDS traffic.
extern "C" __global__ void __launch_bounds__(BLOCK, 2)
lstm_fused2(const float* __restrict__ x,
            const float* __restrict__ Wih0, const float* __restrict__ Whh0,
            const float* __restrict__ bih0, const float* __restrict__ bhh0,
            const float* __restrict__ Wih1, const float* __restrict__ Whh1,
            const float* __restrict__ bih1, const float* __restrict__ bhh1,
            const float* __restrict__ Wfc,  const float* __restrict__ bfc,
            float* __restrict__ out)
{
    __shared__ unsigned short hbuf[2][BT * RS_H]; // per row: [0:64)=h0, [64:128)=h1 (bf16)
    __shared__ float hfin[BT * RS_F];             // final h1 fp32 for the FC head

    const int tid   = threadIdx.x;
    const int b0    = blockIdx.x * BT;
    const int lane  = tid & 63;
    const int wv    = tid >> 6;
    const int layer = wv >> 2;       // 0 or 1
    const int cb    = (wv & 3) * 16; // column base within this layer's 64 h-cols
    const int n16   = lane & 15;
    const int quad  = lane >> 4;

    for (int i = tid; i < 2 * BT * RS_H; i += BLOCK)
        ((unsigned short*)hbuf)[i] = 0;

    // ---- hoisted weight fragments: wf[g][s] for gate g in {i,f,g,o}, source s.
    // L0: s0,s1 = Whh0 (K=64), s2 = sparse Wih0 (x in k=0..3), s3 = zero.
    // L1: s0,s1 = Wih1 (h0 path), s2,s3 = Whh1 (h1 path).
    bf16x8 wf[4][4];
    float bias[4];
    if (layer == 0) {
#pragma unroll
        for (int g = 0; g < 4; ++g) {
            const int gc = g * 64 + cb + n16;
            wf[g][0] = load_wfrag(Whh0 + gc * 64, quad * 8);
            wf[g][1] = load_wfrag(Whh0 + gc * 64, 32 + quad * 8);
            union { bf16x8 v; unsigned short s[8]; } u;
            u.s[0] = (quad == 0) ? f2bf(Wih0[gc * 4 + 0]) : (unsigned short)0;
            u.s[1] = (quad == 0) ? f2bf(Wih0[gc * 4 + 1]) : (unsigned short)0;
            u.s[2] = (quad == 0) ? f2bf(Wih0[gc * 4 + 2]) : (unsigned short)0;
            u.s[3] = (quad == 0) ? f2bf(Wih0[gc * 4 + 3]) : (unsigned short)0;
            u.s[4] = 0; u.s[5] = 0; u.s[6] = 0; u.s[7] = 0;
            wf[g][2] = u.v;
            union { bf16x8 v; unsigned short s[8]; } z;
            z.s[0]=0; z.s[1]=0; z.s[2]=0; z.s[3]=0; z.s[4]=0; z.s[5]=0; z.s[6]=0; z.s[7]=0;
            wf[g][3] = z.v;
            bias[g] = bih0[gc] + bhh0[gc];
        }
    } else {
#pragma unroll
        for (int g = 0; g < 4; ++g) {
            const int gc = g * 64 + cb + n16;
            wf[g][0] = load_wfrag(Wih1 + gc * 64, quad * 8);
            wf[g][1] = load_wfrag(Wih1 + gc * 64, 32 + quad * 8);
            wf[g][2] = load_wfrag(Whh1 + gc * 64, quad * 8);
            wf[g][3] = load_wfrag(Whh1 + gc * 64, 32 + quad * 8);
            bias[g] = bih1[gc] + bhh1[gc];
        }
    }

    float cst[4] = {0.f, 0.f, 0.f, 0.f};   // cell state for 4 rows (m = quad*4+r)
    const f32x4* __restrict__ xv = (const f32x4*)x;   // x[b][t][0:4] = one 16B vector

    __syncthreads();

    for (int it = 0; it <= 512; ++it) {
        const unsigned short* rb = &hbuf[(it + 1) & 1][0];  // prev-state buffer
        unsigned short*       wb = &hbuf[it & 1][0];        // new-state buffer

        // x prefetch for L0 (issued early; ~200cy L2 latency hidden under ds_read+MFMA)
        f32x4 xt = {0.f, 0.f, 0.f, 0.f};
        if (layer == 0) {
            const int t = (it < 512) ? it : 511;  // clamp avoids OOB on the dead last iter
            xt = xv[(size_t)(b0 + n16) * 512 + t];
        }

        // A-fragments: A[m = n16][k = quad*8 + j]
        bf16x8 a0 = *(const bf16x8*)(rb + n16 * RS_H + quad * 8);        // h0 k=0..31
        bf16x8 a1 = *(const bf16x8*)(rb + n16 * RS_H + 32 + quad * 8);   // h0 k=32..63
        bf16x8 a2, a3;
        if (layer == 0) {
            union { bf16x8 v; unsigned short s[8]; } u;
            u.s[0] = (quad == 0) ? f2bf(xt[0]) : (unsigned short)0;
            u.s[1] = (quad == 0) ? f2bf(xt[1]) : (unsigned short)0;
            u.s[2] = (quad == 0) ? f2bf(xt[2]) : (unsigned short)0;
            u.s[3] = (quad == 0) ? f2bf(xt[3]) : (unsigned short)0;
            u.s[4] = 0; u.s[5] = 0; u.s[6] = 0; u.s[7] = 0;
            a2 = u.v;            // x in k=0..3, pairs with sparse Wih0 frag
            a3 = u.v;            // multiplied by zero weights -> contributes 0
        } else {
            a2 = *(const bf16x8*)(rb + n16 * RS_H + 64 + quad * 8);      // h1 k=0..31
            a3 = *(const bf16x8*)(rb + n16 * RS_H + 96 + quad * 8);      // h1 k=32..63
        }

        f32x4 acc[4];
#pragma unroll
        for (int g = 0; g < 4; ++g) {
            acc[g] = (f32x4){bias[g], bias[g], bias[g], bias[g]};
            acc[g] = __builtin_amdgcn_mfma_f32_16x16x32_bf16(a0, wf[g][0], acc[g], 0, 0, 0);
            acc[g] = __builtin_amdgcn_mfma_f32_16x16x32_bf16(a1, wf[g][1], acc[g], 0, 0, 0);
            acc[g] = __builtin_amdgcn_mfma_f32_16x16x32_bf16(a2, wf[g][2], acc[g], 0, 0, 0);
            acc[g] = __builtin_amdgcn_mfma_f32_16x16x32_bf16(a3, wf[g][3], acc[g], 0, 0, 0);
        }

        // in-register LSTM elementwise on the MFMA accumulators
        const bool active = layer ? (it >= 1) : (it < 512);
        if (active) {
#pragma unroll
            for (int r = 0; r < 4; ++r) {
                const float iv = sigm(acc[0][r]);
                const float fv = sigm(acc[1][r]);
                const float gv = tanh_fast(acc[2][r]);
                const float ov = sigm(acc[3][r]);
                const float cc = fv * cst[r] + iv * gv;
                cst[r] = cc;
                const float hh = ov * tanh_fast(cc);
                const int row = quad * 4 + r;
                wb[row * RS_H + layer * 64 + cb + n16] = f2bf(hh);
                if (layer == 1 && it == 512) hfin[row * RS_F + cb + n16] = hh;
            }
        }
        __syncthreads();   // the ONLY barrier per iteration (ping-pong makes it safe)
    }

    // FC head: out[b0+m][k] = h1_final[m,:] . Wfc[k,:] + bfc[k]
    if (tid < BT * 20) {
        const int m = tid / 20, k = tid % 20;
        float acc = bfc[k];
#pragma unroll 8
        for (int j = 0; j < 64; ++j)
            acc += hfin[m * RS_F + j] * Wfc[k * 64 + j];
        out[(b0 + m) * 20 + k] = acc;
    }
}

extern "C" void kernel_launch(void* const* d_in, const int* in_sizes, int n_in,
                              void* d_out, int out_size, void* d_ws, size_t ws_size,
                              hipStream_t stream)
{
    (void)in_sizes; (void)n_in; (void)d_ws; (void)ws_size; (void)out_size;
    const float* xp    = (const float*)d_in[0];
    const float* Wih0p = (const float*)d_in[1];
    const float* Whh0p = (const float*)d_in[2];
    const float* bih0p = (const float*)d_in[3];
    const float* bhh0p = (const float*)d_in[4];
    const float* Wih1p = (const float*)d_in[5];
    const float* Whh1p = (const float*)d_in[6];
    const float* bih1p = (const float*)d_in[7];
    const float* bhh1p = (const float*)d_in[8];
    const float* Wfcp  = (const float*)d_in[9];
    const float* bfcp  = (const float*)d_in[10];

    lstm_fused2<<<dim3(256), dim3(BLOCK), 0, stream>>>(
        xp, Wih0p, Whh0p, bih0p, bhh0p, Wih1p, Whh1p, bih1p, bhh1p,
        Wfcp, bfcp, (float*)d_out);
}

// Round 3
// 508.367 us; speedup vs baseline: 1.6884x; 1.1187x over previous
//
#include <hip/hip_runtime.h>
#include <cstdint>

#define BLOCK 512
#define BT 16            // batch rows per block (grid = 4096/16 = 256 = 1 block/CU)
#define RS_H 136         // h row stride in bf16 elems: 128 data (h0|h1) + 8 pad
#define RS_F 68          // hfin row stride (fp32)

typedef __attribute__((ext_vector_type(8))) short bf16x8;
typedef __attribute__((ext_vector_type(4))) float f32x4;

#define LOG2E 1.44269504f

static __device__ __forceinline__ float exp2_fast(float x) {
#if __has_builtin(__builtin_amdgcn_exp2f)
    return __builtin_amdgcn_exp2f(x);
#else
    return __expf(x * 0.69314718056f);
#endif
}
static __device__ __forceinline__ float rcp_fast(float x) {
    return __builtin_amdgcn_rcpf(x);
}
static __device__ __forceinline__ unsigned short f2bf(float f) {
    union { float f; unsigned u; } v; v.f = f;
    unsigned r = v.u + 0x7fffu + ((v.u >> 16) & 1u);   // RNE
    return (unsigned short)(r >> 16);
}
// sigmoid of pre-activation given y = -log2e * pre
static __device__ __forceinline__ float sigm_y(float y) {
    return rcp_fast(1.0f + exp2_fast(y));
}
// tanh of pre-activation given y = 2*log2e * pre
static __device__ __forceinline__ float tanh_y(float y) {
    return 1.0f - 2.0f * rcp_fast(exp2_fast(y) + 1.0f);
}
static __device__ __forceinline__ bf16x8 load_wfrag(const float* __restrict__ w, int off, float scale) {
    union { bf16x8 v; unsigned short s[8]; } u;
#pragma unroll
    for (int j = 0; j < 8; ++j) u.s[j] = f2bf(w[off + j] * scale);
    return u.v;
}

// One block = 16 batch rows. 8 waves: wv>>2 = layer (0/1), wv&3 = 16-col tile.
// Pipeline skew: at iteration `it`, L0-waves compute step it, L1-waves step it-1.
// Ping-pong h buffers => ONE barrier per iteration; eltwise runs on MFMA
// accumulators in-register (C/D layout: col = lane&15, row = quad*4 + reg).
// Gate weights are pre-scaled by -log2e (i,f,o) / +2log2e (g) so activations
// use raw v_exp_f32 with no argument multiply.
extern "C" __global__ void __launch_bounds__(BLOCK, 2)
lstm_fused3(const float* __restrict__ x,
            const float* __restrict__ Wih0, const float* __restrict__ Whh0,
            const float* __restrict__ bih0, const float* __restrict__ bhh0,
            const float* __restrict__ Wih1, const float* __restrict__ Whh1,
            const float* __restrict__ bih1, const float* __restrict__ bhh1,
            const float* __restrict__ Wfc,  const float* __restrict__ bfc,
            float* __restrict__ out)
{
    __shared__ unsigned short hbuf[2][BT * RS_H]; // per row: [0:64)=h0, [64:128)=h1 (bf16)
    __shared__ float hfin[BT * RS_F];             // final h1 fp32 for the FC head

    const int tid   = threadIdx.x;
    const int b0    = blockIdx.x * BT;
    const int lane  = tid & 63;
    const int wv    = tid >> 6;
    const int layer = wv >> 2;       // 0 or 1
    const int cb    = (wv & 3) * 16; // column base within this layer's 64 h-cols
    const int n16   = lane & 15;
    const int quad  = lane >> 4;

    for (int i = tid; i < 2 * BT * RS_H; i += BLOCK)
        ((unsigned short*)hbuf)[i] = 0;

    // gate exponent scales: i,f,o -> -log2e ; g -> +2log2e
    const float gsc[4] = {-LOG2E, -LOG2E, 2.0f * LOG2E, -LOG2E};

    // ---- hoisted weight fragments: wf[g][s], gate g in {i,f,g,o}, source s.
    // L0: s0,s1 = Whh0 (K=64), s2 = sparse Wih0 (x in k=0..3), s3 = zero.
    // L1: s0,s1 = Wih1 (h0 path), s2,s3 = Whh1 (h1 path).
    bf16x8 wf[4][4];
    float bias[4];
    if (layer == 0) {
#pragma unroll
        for (int g = 0; g < 4; ++g) {
            const int gc = g * 64 + cb + n16;
            const float s = gsc[g];
            wf[g][0] = load_wfrag(Whh0 + gc * 64, quad * 8, s);
            wf[g][1] = load_wfrag(Whh0 + gc * 64, 32 + quad * 8, s);
            union { bf16x8 v; unsigned short s_[8]; } u;
#pragma unroll
            for (int c = 0; c < 4; ++c)
                u.s_[c] = (quad == 0) ? f2bf(Wih0[gc * 4 + c] * s) : (unsigned short)0;
            u.s_[4] = 0; u.s_[5] = 0; u.s_[6] = 0; u.s_[7] = 0;
            wf[g][2] = u.v;
            union { bf16x8 v; unsigned short s_[8]; } z;
#pragma unroll
            for (int c = 0; c < 8; ++c) z.s_[c] = 0;
            wf[g][3] = z.v;
            bias[g] = (bih0[gc] + bhh0[gc]) * s;
        }
    } else {
#pragma unroll
        for (int g = 0; g < 4; ++g) {
            const int gc = g * 64 + cb + n16;
            const float s = gsc[g];
            wf[g][0] = load_wfrag(Wih1 + gc * 64, quad * 8, s);
            wf[g][1] = load_wfrag(Wih1 + gc * 64, 32 + quad * 8, s);
            wf[g][2] = load_wfrag(Whh1 + gc * 64, quad * 8, s);
            wf[g][3] = load_wfrag(Whh1 + gc * 64, 32 + quad * 8, s);
            bias[g] = (bih1[gc] + bhh1[gc]) * s;
        }
    }

    float cst[4] = {0.f, 0.f, 0.f, 0.f};   // cell state for 4 rows (m = quad*4+r)

    // x prefetch pipeline: xnext holds x(t) for the upcoming iteration
    const f32x4* __restrict__ xrow = (const f32x4*)x + (size_t)(b0 + n16) * 512;
    f32x4 xnext = {0.f, 0.f, 0.f, 0.f};
    if (layer == 0) xnext = xrow[0];

    __syncthreads();

    for (int it = 0; it <= 512; ++it) {
        const unsigned short* rb = &hbuf[(it + 1) & 1][0];  // prev-state buffer
        unsigned short*       wb = &hbuf[it & 1][0];        // new-state buffer

        const f32x4 xcur = xnext;
        if (layer == 0 && it < 511) xnext = xrow[it + 1];   // consumed NEXT iter

        // A-fragments: A[m = n16][k = quad*8 + j]
        bf16x8 a0 = *(const bf16x8*)(rb + n16 * RS_H + quad * 8);        // h0 k=0..31
        bf16x8 a1 = *(const bf16x8*)(rb + n16 * RS_H + 32 + quad * 8);   // h0 k=32..63
        bf16x8 a2, a3;
        if (layer == 0) {
            union { bf16x8 v; unsigned short s[8]; } u;
            u.s[0] = (quad == 0) ? f2bf(xcur[0]) : (unsigned short)0;
            u.s[1] = (quad == 0) ? f2bf(xcur[1]) : (unsigned short)0;
            u.s[2] = (quad == 0) ? f2bf(xcur[2]) : (unsigned short)0;
            u.s[3] = (quad == 0) ? f2bf(xcur[3]) : (unsigned short)0;
            u.s[4] = 0; u.s[5] = 0; u.s[6] = 0; u.s[7] = 0;
            a2 = u.v;            // x in k=0..3, pairs with sparse Wih0 frag
            a3 = u.v;            // multiplied by zero weights -> contributes 0
        } else {
            a2 = *(const bf16x8*)(rb + n16 * RS_H + 64 + quad * 8);      // h1 k=0..31
            a3 = *(const bf16x8*)(rb + n16 * RS_H + 96 + quad * 8);      // h1 k=32..63
        }

        f32x4 acc[4];
#pragma unroll
        for (int g = 0; g < 4; ++g) {
            acc[g] = (f32x4){bias[g], bias[g], bias[g], bias[g]};
            acc[g] = __builtin_amdgcn_mfma_f32_16x16x32_bf16(a0, wf[g][0], acc[g], 0, 0, 0);
            acc[g] = __builtin_amdgcn_mfma_f32_16x16x32_bf16(a1, wf[g][1], acc[g], 0, 0, 0);
            acc[g] = __builtin_amdgcn_mfma_f32_16x16x32_bf16(a2, wf[g][2], acc[g], 0, 0, 0);
            acc[g] = __builtin_amdgcn_mfma_f32_16x16x32_bf16(a3, wf[g][3], acc[g], 0, 0, 0);
        }

        // in-register LSTM elementwise (acc already carries the exp2 scales)
        const bool active = layer ? (it >= 1) : (it < 512);
        if (active) {
#pragma unroll
            for (int r = 0; r < 4; ++r) {
                const float iv = sigm_y(acc[0][r]);
                const float fv = sigm_y(acc[1][r]);
                const float gv = tanh_y(acc[2][r]);
                const float ov = sigm_y(acc[3][r]);
                const float cc = fv * cst[r] + iv * gv;
                cst[r] = cc;
                const float hh = ov * tanh_y(cc * (2.0f * LOG2E));
                const int row = quad * 4 + r;
                wb[row * RS_H + layer * 64 + cb + n16] = f2bf(hh);
                if (layer == 1 && it == 512) hfin[row * RS_F + cb + n16] = hh;
            }
        }
        __syncthreads();   // the ONLY barrier per iteration (ping-pong makes it safe)
    }

    // FC head: out[b0+m][k] = h1_final[m,:] . Wfc[k,:] + bfc[k]
    if (tid < BT * 20) {
        const int m = tid / 20, k = tid % 20;
        float acc = bfc[k];
#pragma unroll 8
        for (int j = 0; j < 64; ++j)
            acc += hfin[m * RS_F + j] * Wfc[k * 64 + j];
        out[(b0 + m) * 20 + k] = acc;
    }
}

extern "C" void kernel_launch(void* const* d_in, const int* in_sizes, int n_in,
                              void* d_out, int out_size, void* d_ws, size_t ws_size,
                              hipStream_t stream)
{
    (void)in_sizes; (void)n_in; (void)d_ws; (void)ws_size; (void)out_size;
    const float* xp    = (const float*)d_in[0];
    const float* Wih0p = (const float*)d_in[1];
    const float* Whh0p = (const float*)d_in[2];
    const float* bih0p = (const float*)d_in[3];
    const float* bhh0p = (const float*)d_in[4];
    const float* Wih1p = (const float*)d_in[5];
    const float* Whh1p = (const float*)d_in[6];
    const float* bih1p = (const float*)d_in[7];
    const float* bhh1p = (const float*)d_in[8];
    const float* Wfcp  = (const float*)d_in[9];
    const float* bfcp  = (const float*)d_in[10];

    lstm_fused3<<<dim3(256), dim3(BLOCK), 0, stream>>>(
        xp, Wih0p, Whh0p, bih0p, bhh0p, Wih1p, Whh1p, bih1p, bhh1p,
        Wfcp, bfcp, (float*)d_out);
}